// Round 7
// baseline (723.715 us; speedup 1.0000x reference)
//
#include <hip/hip_runtime.h>

#define BT 51200      // B*T
#define NB 512        // batch

// ---------- workspace float offsets ----------
#define P1_OFF   ((size_t)0)
#define X_OFF    ((size_t)20480000)
#define GX_OFF   ((size_t)0)
#define SM_OFF   ((size_t)27033600)

__device__ __forceinline__ float sigf(float x) {
  return __fdividef(1.f, 1.f + __expf(-x));
}
__device__ __forceinline__ float tanhf2(float x) {
  float ax = fabsf(x);
  float e = __expf(-2.f * ax);
  float r = __fdividef(1.f - e, 1.f + e);
  return x < 0.f ? -r : r;
}

// ================= K1: conv1 (SAME 3x3, C=4->16) + relu + 2x2 maxpool =====
// Round-6 fix: __launch_bounds__(1024,4) did NOT stop the allocator from
// squeezing to 64 VGPR (2nd arg is a MIN waves/EU -> only an upper cap on
// VGPRs; fewer regs never violates it). Result: still spilling (WRITE
// 115MB vs 91 ideal). amdgpu_waves_per_eu(4,4) sets min AND MAX: with max=4
// the budget is 512/4=128 VGPR and there is no incentive to shrink below
// the ~105 live set -> no spill, same 16-wave TLP.
__global__ __attribute__((amdgpu_flat_work_group_size(1024, 1024)))
__attribute__((amdgpu_waves_per_eu(4, 4)))
void k1_conv1(const float* __restrict__ obs, const float* __restrict__ w,
              const float* __restrict__ bias, float* __restrict__ p1) {
  __shared__ float xs[64 * 401];
  int tid = threadIdx.x;
  int i0 = blockIdx.x * 64;
  // staging: same pattern as round 0/4 (FETCH 44MB, 25600 conflicts)
  for (int idx = tid; idx < 25600; idx += 1024) {
    int item = idx / 400, feat = idx - item * 400;
    xs[item * 401 + feat] = obs[(size_t)(i0 + item) * 400 + feat];
  }
  __syncthreads();
  int lane = tid & 63;
  int wv = __builtin_amdgcn_readfirstlane(tid >> 6);  // 0..15 = output channel
  const float* xrow = xs + lane * 401;

// load one padded input row (c=C, row index RR within the 4-row band) into R
#define LOADR(R, C, RR) do { \
  int r_ = 2 * p - 1 + (RR); \
  R[0] = 0.f; R[11] = 0.f; \
  if (r_ >= 0 && r_ <= 9) { \
    _Pragma("unroll") \
    for (int j = 0; j < 10; ++j) R[j + 1] = xrow[(C) * 100 + r_ * 10 + j]; \
  } else { \
    _Pragma("unroll") \
    for (int j = 0; j < 10; ++j) R[j + 1] = 0.f; \
  } \
} while (0)

// one FMA unit: output-row-pair II of channel C from rows RA,RB,RC (90 FMA)
// weights via uniform pointer -> s_load -> SGPR operand in v_fma
#define FMAU(II, RA, RB, RC, C) do { \
  const float* wa_ = w + wv * 36 + (C) * 9; \
  _Pragma("unroll") \
  for (int q = 0; q < 5; ++q) { \
    _Pragma("unroll") \
    for (int jj = 0; jj < 2; ++jj) { \
      int cb = 2 * q + jj; \
      acc[q][II][jj] += RA[cb] * wa_[0] + RA[cb + 1] * wa_[1] + RA[cb + 2] * wa_[2] \
                      + RB[cb] * wa_[3] + RB[cb + 1] * wa_[4] + RB[cb + 2] * wa_[5] \
                      + RC[cb] * wa_[6] + RC[cb + 1] * wa_[7] + RC[cb + 2] * wa_[8]; \
    } \
  } \
} while (0)

  float b0 = bias[wv];

#pragma unroll 1
  for (int p = 0; p < 5; ++p) {
    float acc[5][2][2];
#pragma unroll
    for (int q = 0; q < 5; ++q)
#pragma unroll
      for (int ii = 0; ii < 2; ++ii)
#pragma unroll
        for (int jj = 0; jj < 2; ++jj) acc[q][ii][jj] = b0;
    float R0[12], R1[12], R2[12], R3[12], R4[12], R5[12];
    // stream s0..s15 = (c0,r0..3)(c1,r0..3)(c2,r0..3)(c3,r0..3), buf = s%6
    LOADR(R0, 0, 0); LOADR(R1, 0, 1); LOADR(R2, 0, 2);  // s0,s1,s2
    LOADR(R3, 0, 3); LOADR(R4, 1, 0);                   // s3,s4
    FMAU(0, R0, R1, R2, 0);                             // U0
    LOADR(R5, 1, 1); LOADR(R0, 1, 2);                   // s5,s6
    FMAU(1, R1, R2, R3, 0);                             // U1
    LOADR(R1, 1, 3); LOADR(R2, 2, 0);                   // s7,s8
    FMAU(0, R4, R5, R0, 1);                             // U2
    LOADR(R3, 2, 1); LOADR(R4, 2, 2);                   // s9,s10
    FMAU(1, R5, R0, R1, 1);                             // U3
    LOADR(R5, 2, 3); LOADR(R0, 3, 0);                   // s11,s12
    FMAU(0, R2, R3, R4, 2);                             // U4
    LOADR(R1, 3, 1); LOADR(R2, 3, 2);                   // s13,s14
    FMAU(1, R3, R4, R5, 2);                             // U5
    LOADR(R3, 3, 3);                                    // s15
    FMAU(0, R0, R1, R2, 3);                             // U6
    FMAU(1, R1, R2, R3, 3);                             // U7
    // 2x2 maxpool + relu + store (256B segments per (p,q))
#pragma unroll
    for (int q = 0; q < 5; ++q) {
      float m = fmaxf(fmaxf(acc[q][0][0], acc[q][0][1]),
                      fmaxf(acc[q][1][0], acc[q][1][1]));
      m = fmaxf(m, 0.f);
      p1[(size_t)(wv * 25 + p * 5 + q) * BT + i0 + lane] = m;
    }
  }
#undef LOADR
#undef FMAU
}

// ================= K2: conv2 (SAME 3x3, 16->32) + relu + 2x2 maxpool ======
__global__ __launch_bounds__(256, 2)
void k2_conv2(const float* __restrict__ p1, const float* __restrict__ w,
              const float* __restrict__ bias, float* __restrict__ x) {
  int item = blockIdx.x * 256 + threadIdx.x;
  int oc = blockIdx.y;
  float acc[8][16];
#pragma unroll
  for (int o = 0; o < 8; ++o) {
    float bv = bias[oc * 8 + o];
#pragma unroll
    for (int pos = 0; pos < 16; ++pos) acc[o][pos] = bv;
  }
#pragma unroll 1
  for (int c = 0; c < 16; ++c) {
    float in[6][6];
#pragma unroll
    for (int t = 0; t < 6; ++t) { in[0][t] = 0.f; in[t][0] = 0.f; }
#pragma unroll
    for (int i = 0; i < 5; ++i)
#pragma unroll
      for (int j = 0; j < 5; ++j)
        in[i + 1][j + 1] = p1[(size_t)(c * 25 + i * 5 + j) * BT + item];
#pragma unroll
    for (int o = 0; o < 8; ++o) {
#pragma unroll
      for (int i = 0; i < 4; ++i)
#pragma unroll
        for (int j = 0; j < 4; ++j) {
          float a = acc[o][i * 4 + j];
#pragma unroll
          for (int dr = 0; dr < 3; ++dr)
#pragma unroll
            for (int dj = 0; dj < 3; ++dj)
              a += in[i + dr][j + dj] * w[((oc * 8 + o) * 16 + c) * 9 + dr * 3 + dj];
          acc[o][i * 4 + j] = a;
        }
    }
  }
#pragma unroll
  for (int o = 0; o < 8; ++o)
#pragma unroll
    for (int p = 0; p < 2; ++p)
#pragma unroll
      for (int q = 0; q < 2; ++q) {
        float m = fmaxf(fmaxf(acc[o][(2 * p) * 4 + 2 * q], acc[o][(2 * p) * 4 + 2 * q + 1]),
                        fmaxf(acc[o][(2 * p + 1) * 4 + 2 * q], acc[o][(2 * p + 1) * 4 + 2 * q + 1]));
        m = fmaxf(m, 0.f);
        x[(size_t)((oc * 8 + o) * 4 + p * 2 + q) * BT + item] = m;
      }
}

// ================= K3: fc1(+bn,relu) -> fc2(+bn,relu) -> eWih projection ===
__global__ __launch_bounds__(256, 2)
void k3_fc(const float* __restrict__ x,
           const float* __restrict__ f1w, const float* __restrict__ f1b,
           const float* __restrict__ bn1g, const float* __restrict__ bn1b,
           const float* __restrict__ f2w, const float* __restrict__ f2b,
           const float* __restrict__ bn2g, const float* __restrict__ bn2b,
           const float* __restrict__ eWih, const float* __restrict__ ebih,
           const float* __restrict__ ebhh, float* __restrict__ gx) {
  __shared__ float xs[128 * 64];
  __shared__ float ys[128 * 64];
  const float BNRS = 0.9999950000374997f;  // 1/sqrt(1+1e-5)
  int tid = threadIdx.x;
  int lane = tid & 63;
  int wv = __builtin_amdgcn_readfirstlane(tid >> 6);
  int i0 = blockIdx.x * 64;
#pragma unroll
  for (int r = 0; r < 32; ++r) {
    int k = r * 4 + (tid >> 6);
    xs[k * 64 + lane] = x[(size_t)k * BT + i0 + lane];
  }
  __syncthreads();
#pragma unroll 1
  for (int jj = 0; jj < 8; ++jj) {
    int j0 = wv * 32 + jj * 4;
    float a[4] = {0.f, 0.f, 0.f, 0.f};
#pragma unroll 8
    for (int k = 0; k < 128; ++k) {
      float xv = xs[k * 64 + lane];
#pragma unroll
      for (int u = 0; u < 4; ++u) a[u] += xv * f1w[(j0 + u) * 128 + k];
    }
#pragma unroll
    for (int u = 0; u < 4; ++u) {
      int j = j0 + u;
      float v = a[u] + f1b[j];
      v = bn1g[j] * v * BNRS + bn1b[j];
      ys[j * 64 + lane] = fmaxf(v, 0.f);
    }
  }
  __syncthreads();
#pragma unroll 1
  for (int jj = 0; jj < 4; ++jj) {
    int j0 = wv * 16 + jj * 4;
    float a[4] = {0.f, 0.f, 0.f, 0.f};
#pragma unroll 8
    for (int k = 0; k < 128; ++k) {
      float yv = ys[k * 64 + lane];
#pragma unroll
      for (int u = 0; u < 4; ++u) a[u] += yv * f2w[(j0 + u) * 128 + k];
    }
#pragma unroll
    for (int u = 0; u < 4; ++u) {
      int j = j0 + u;
      float v = a[u] + f2b[j];
      v = bn2g[j] * v * BNRS + bn2b[j];
      xs[j * 64 + lane] = fmaxf(v, 0.f);
    }
  }
  __syncthreads();
#pragma unroll 1
  for (int jj = 0; jj < 8; ++jj) {
    int j0 = wv * 32 + jj * 4;
    float a[4] = {0.f, 0.f, 0.f, 0.f};
#pragma unroll 8
    for (int k = 0; k < 64; ++k) {
      float zv = xs[k * 64 + lane];
#pragma unroll
      for (int u = 0; u < 4; ++u) a[u] += zv * eWih[(j0 + u) * 64 + k];
    }
#pragma unroll
    for (int u = 0; u < 4; ++u) {
      int j = j0 + u;
      gx[(size_t)j * BT + i0 + lane] = a[u] + ebih[j] + ebhh[j];
    }
  }
}

// ================= K4: encoder LSTM (T=100), one wave per batch ===========
__global__ __launch_bounds__(64, 4)
void k4_enc(const float* __restrict__ gx, const float* __restrict__ eWhh,
            float* __restrict__ dh, float* __restrict__ dc) {
  __shared__ float wT[32 * 128];  // [k][gate]
  int lane = threadIdx.x;
  int b = blockIdx.x;
#pragma unroll 1
  for (int r = 0; r < 64; ++r) {
    int idx = lane + r * 64;
    int g = idx & 127, k = idx >> 7;
    wT[k * 128 + g] = eWhh[g * 32 + k];
  }
  __syncthreads();
  float c = 0.f, h = 0.f;
  size_t base0 = (size_t)b * 100;
  float ga_n = gx[(size_t)lane * BT + base0];
  float gb_n = gx[(size_t)(lane + 64) * BT + base0];
  int xl = (lane & 31) + 32;
#pragma unroll 1
  for (int t = 0; t < 100; ++t) {
    float ga = ga_n, gb2 = gb_n;
    if (t < 99) {
      ga_n = gx[(size_t)lane * BT + base0 + t + 1];
      gb_n = gx[(size_t)(lane + 64) * BT + base0 + t + 1];
    }
#pragma unroll
    for (int k = 0; k < 32; ++k) {
      float hk = __shfl(h, k);
      ga += hk * wT[k * 128 + lane];
      gb2 += hk * wT[k * 128 + lane + 64];
    }
    float gaX = __shfl(ga, xl);   // gate lane+32 (f for lanes<32)
    float gbX = __shfl(gb2, xl);  // gate lane+96 (o for lanes<32)
    if (lane < 32) {
      float ig = sigf(ga);
      float fg = sigf(gaX);
      float gg = tanhf2(gb2);
      float og = sigf(gbX);
      c = fg * c + ig * gg;
      h = og * tanhf2(c);
    }
  }
  if (lane < 32) {
    dh[b * 32 + lane] = h;
    dc[b * 32 + lane] = c;
  }
}

// ====== K5: decoder LSTM (din==dh identity) + physics + Q/R LSTMs =========
__global__ __launch_bounds__(256, 2)
void k5_dec(const float* __restrict__ obs,
            const float* __restrict__ dWih, const float* __restrict__ dWhh,
            const float* __restrict__ dbih, const float* __restrict__ dbhh,
            const float* __restrict__ ow, const float* __restrict__ ob,
            const float* __restrict__ qWih, const float* __restrict__ qWhh,
            const float* __restrict__ qbih, const float* __restrict__ qbhh,
            const float* __restrict__ qfw, const float* __restrict__ qfb,
            const float* __restrict__ rWih, const float* __restrict__ rWhh,
            const float* __restrict__ rbih, const float* __restrict__ rbhh,
            const float* __restrict__ rfw, const float* __restrict__ rfb,
            const float* __restrict__ dh0, const float* __restrict__ dc0,
            float* __restrict__ traj, float* __restrict__ qdg, float* __restrict__ rdg) {
  __shared__ float dwT[32 * 128], qihT[24 * 128], qhhT[32 * 128], rihT[24 * 128], rhhT[32 * 128];
  __shared__ float owT[32 * 12], qfwT[32 * 24], rfwT[32 * 24];
  __shared__ float dbs[128], qbs[128], rbs[128];
  __shared__ float tL4[4 * 120];
  int tid = threadIdx.x;
  for (int idx = tid; idx < 4096; idx += 256) {
    int k = idx >> 7, g = idx & 127;
    dwT[idx] = dWih[g * 32 + k] + dWhh[g * 32 + k];  // din==dh every step
    qhhT[idx] = qWhh[g * 32 + k];
    rhhT[idx] = rWhh[g * 32 + k];
  }
  for (int idx = tid; idx < 3072; idx += 256) {
    int k = idx >> 7, g = idx & 127;
    qihT[idx] = qWih[g * 24 + k];
    rihT[idx] = rWih[g * 24 + k];
  }
  for (int idx = tid; idx < 384; idx += 256) {
    int k = idx / 12, j = idx - k * 12;
    owT[idx] = ow[j * 32 + k];
  }
  for (int idx = tid; idx < 768; idx += 256) {
    int k = idx / 24, j = idx - k * 24;
    qfwT[idx] = qfw[j * 32 + k];
    rfwT[idx] = rfw[j * 32 + k];
  }
  for (int idx = tid; idx < 128; idx += 256) {
    dbs[idx] = dbih[idx] + dbhh[idx];
    qbs[idx] = qbih[idx] + qbhh[idx];
    rbs[idx] = rbih[idx] + rbhh[idx];
  }
  __syncthreads();
  int lane = tid & 63, w = tid >> 6, b = blockIdx.x * 4 + w;
  float* tL = tL4 + w * 120;
  int xl = (lane & 31) + 32;
  int l12 = lane < 12 ? lane : 0;
  int l24 = lane < 24 ? lane : 0;
  float cc = 0.f, hh = 0.f;
  if (lane < 32) {
    hh = dh0[b * 32 + lane];
    cc = dc0[b * 32 + lane];
  }
  float aReg[5];
  // decoder: 5 steps
#pragma unroll 1
  for (int s = 0; s < 5; ++s) {
    float ga = dbs[lane], gb2 = dbs[lane + 64];
#pragma unroll
    for (int k = 0; k < 32; ++k) {
      float hk = __shfl(hh, k);
      ga += hk * dwT[k * 128 + lane];
      gb2 += hk * dwT[k * 128 + lane + 64];
    }
    float gaX = __shfl(ga, xl);
    float gbX = __shfl(gb2, xl);
    if (lane < 32) {
      float ig = sigf(ga), fg = sigf(gaX);
      float gg = tanhf2(gb2), og = sigf(gbX);
      cc = fg * cc + ig * gg;
      hh = og * tanhf2(cc);
    }
    float pa = ob[l12];
#pragma unroll
    for (int k = 0; k < 32; ++k) pa += __shfl(hh, k) * owT[k * 12 + l12];
    aReg[s] = pa;
  }
  // physics integration -> tL (traj)
  if (lane < 12) {
    int n = lane >> 1, d = lane & 1;
    float v0 = 0.f, p0 = 0.f;
    if (n == 0) {
      p0 = obs[(size_t)b * 40000 + 39600 + d];
      v0 = obs[(size_t)b * 40000 + 39600 + 2 + d];
    }
    float vc = v0, pc = p0;
#pragma unroll
    for (int s = 0; s < 5; ++s) {
      float a = aReg[s];
      vc += 0.1f * a;
      pc += vc * 0.1f + a * 0.005f;
      tL[s * 24 + n * 4 + d] = pc;
      tL[s * 24 + n * 4 + 2 + d] = vc;
    }
  }
  __syncthreads();
#pragma unroll
  for (int e = 0; e < 2; ++e) {
    int idx = lane + 64 * e;
    if (idx < 120) traj[(size_t)b * 120 + idx] = tL[idx];
  }
  // Q then R LSTM over traj
#pragma unroll 1
  for (int qr = 0; qr < 2; ++qr) {
    const float* ihT = qr ? rihT : qihT;
    const float* hhT = qr ? rhhT : qhhT;
    const float* bs = qr ? rbs : qbs;
    const float* fwT = qr ? rfwT : qfwT;
    const float* fbg = qr ? rfb : qfb;
    float* outg = qr ? rdg : qdg;
    hh = 0.f;
    cc = 0.f;
#pragma unroll 1
    for (int s = 0; s < 5; ++s) {
      float ga = bs[lane], gb2 = bs[lane + 64];
#pragma unroll
      for (int k = 0; k < 24; ++k) {
        float z = tL[s * 24 + k];
        ga += z * ihT[k * 128 + lane];
        gb2 += z * ihT[k * 128 + lane + 64];
      }
#pragma unroll
      for (int k = 0; k < 32; ++k) {
        float hk = __shfl(hh, k);
        ga += hk * hhT[k * 128 + lane];
        gb2 += hk * hhT[k * 128 + lane + 64];
      }
      float gaX = __shfl(ga, xl);
      float gbX = __shfl(gb2, xl);
      if (lane < 32) {
        float ig = sigf(ga), fg = sigf(gaX);
        float gg = tanhf2(gb2), og = sigf(gbX);
        cc = fg * cc + ig * gg;
        hh = og * tanhf2(cc);
      }
    }
    float qv = fbg[l24];
#pragma unroll
    for (int k = 0; k < 32; ++k) qv += __shfl(hh, k) * fwT[k * 24 + l24];
    if (lane < 24) outg[b * 24 + lane] = fabsf(qv);
  }
}

// ================= K6: Kalman filter, register-resident, one wave/batch ===
// Column-per-lane layout: lane j<24 holds P column j; aug matrix [S | Pm]
// columns on lanes 0..47. All cross-lane via __shfl; no LDS, no barriers.
// Uses S = Pm + diag(R) symmetric => solve(S,Pm^T) = S^{-1} Pm.
__global__ __launch_bounds__(64, 1)
void k6_kf(const float* __restrict__ obs, const float* __restrict__ traj,
           const float* __restrict__ qd, const float* __restrict__ rd,
           float* __restrict__ out) {
  int lane = threadIdx.x;
  int b = blockIdx.x;
  int l24 = (lane < 24) ? lane : 0;
  float sv = 0.f, qv = 0.f, rv = 0.f;
  if (lane < 24) {
    sv = (lane < 4) ? obs[(size_t)b * 40000 + 39600 + lane] : 0.f;
    qv = qd[b * 24 + lane];
    rv = rd[b * 24 + lane];
  }
  float p[24];
#pragma unroll
  for (int i = 0; i < 24; ++i) p[i] = (i == lane) ? 1.f : 0.f;
  const int srcPF = ((lane & 3) < 2) ? (lane + 2) : lane;  // in-range for all 64 lanes
  const int srcA = (lane < 24) ? lane : (lane - 24);
#pragma unroll 1
  for (int s = 0; s < 5; ++s) {
    // ---- s_m = F s ----
    float sshift = __shfl(sv, srcPF);
    float smv = sv + (((lane & 3) < 2) ? 0.1f * sshift : 0.f);
    // ---- P <- F P (row update, lane-local) ----
#pragma unroll
    for (int i = 0; i < 24; ++i)
      if ((i & 3) < 2) p[i] += 0.1f * p[i + 2];
    // ---- P <- P F^T (column update via shfl from col j+2) ----
#pragma unroll
    for (int i = 0; i < 24; ++i) {
      float t = __shfl(p[i], srcPF);
      if ((lane & 3) < 2) p[i] += 0.1f * t;
    }
    // ---- + Qm (diagonal) ----
#pragma unroll
    for (int i = 0; i < 24; ++i) p[i] += (i == lane) ? qv : 0.f;
    // ---- build aug [S | Pm]: lanes<24 S col, lanes 24..47 Pm col ----
    float a[24];
#pragma unroll
    for (int i = 0; i < 24; ++i) {
      float t = __shfl(p[i], srcA);
      a[i] = (lane < 24) ? (p[i] + ((i == lane) ? rv : 0.f)) : t;
    }
    // ---- Gauss-Jordan, no pivoting (S SPD) ----
#pragma unroll
    for (int k = 0; k < 24; ++k) {
      float piv = __shfl(a[k], k);
      float inv = 1.f / piv;
      float t = a[k] * inv;   // new row-k element in this column
#pragma unroll
      for (int i = 0; i < 24; ++i) {
        if (i != k) {
          float fi = __shfl(a[i], k);  // old ag[i][k] (lane k not yet updated)
          a[i] = fmaf(-fi, t, a[i]);
        }
      }
      a[k] = t;
    }
    // lanes 24+j now hold X = S^{-1} Pm column j;  K = X^T
    // ---- innovation & state update ----
    float zv = traj[(size_t)b * 120 + s * 24 + l24];
    float innv = zv - smv;  // valid on lanes<24 (shfl sources)
    float acc = 0.f;
#pragma unroll
    for (int m = 0; m < 24; ++m) acc += a[m] * __shfl(innv, m);
    float kupd = __shfl(acc, 24 + l24);  // lane i<24 pulls from lane 24+i
    sv = smv + kupd;
    if (lane < 24) out[(size_t)b * 120 + s * 24 + lane] = sv;
    // ---- P_new = Pm - X^T Pm : pn[i] = p[i] - sum_k X[k][i]*p[k] ----
    float pn[24];
#pragma unroll
    for (int i = 0; i < 24; ++i) {
      float acc2 = 0.f;
#pragma unroll
      for (int k = 0; k < 24; ++k) acc2 += __shfl(a[k], 24 + i) * p[k];
      pn[i] = p[i] - acc2;
    }
#pragma unroll
    for (int i = 0; i < 24; ++i) p[i] = pn[i];
  }
}

// =========================================================================
extern "C" void kernel_launch(void* const* d_in, const int* in_sizes, int n_in,
                              void* d_out, int out_size, void* d_ws, size_t ws_size,
                              hipStream_t stream) {
  (void)in_sizes; (void)n_in; (void)out_size; (void)ws_size;
  const float* obs  = (const float*)d_in[0];
  const float* c1w  = (const float*)d_in[1];
  const float* c1b  = (const float*)d_in[2];
  const float* c2w  = (const float*)d_in[3];
  const float* c2b  = (const float*)d_in[4];
  const float* f1w  = (const float*)d_in[5];
  const float* f1b  = (const float*)d_in[6];
  const float* bn1g = (const float*)d_in[7];
  const float* bn1b = (const float*)d_in[8];
  const float* f2w  = (const float*)d_in[9];
  const float* f2b  = (const float*)d_in[10];
  const float* bn2g = (const float*)d_in[11];
  const float* bn2b = (const float*)d_in[12];
  const float* eWih = (const float*)d_in[13];
  const float* eWhh = (const float*)d_in[14];
  const float* ebih = (const float*)d_in[15];
  const float* ebhh = (const float*)d_in[16];
  const float* dWih = (const float*)d_in[17];
  const float* dWhh = (const float*)d_in[18];
  const float* dbih = (const float*)d_in[19];
  const float* dbhh = (const float*)d_in[20];
  const float* ow   = (const float*)d_in[21];
  const float* ob   = (const float*)d_in[22];
  const float* qWih = (const float*)d_in[23];
  const float* qWhh = (const float*)d_in[24];
  const float* qbih = (const float*)d_in[25];
  const float* qbhh = (const float*)d_in[26];
  const float* qfw  = (const float*)d_in[27];
  const float* qfb  = (const float*)d_in[28];
  const float* rWih = (const float*)d_in[29];
  const float* rWhh = (const float*)d_in[30];
  const float* rbih = (const float*)d_in[31];
  const float* rbhh = (const float*)d_in[32];
  const float* rfw  = (const float*)d_in[33];
  const float* rfb  = (const float*)d_in[34];

  float* ws = (float*)d_ws;
  float* p1   = ws + P1_OFF;
  float* x    = ws + X_OFF;
  float* gx   = ws + GX_OFF;       // reuses p1 region (dead after k2)
  float* dh   = ws + SM_OFF;
  float* dc   = dh + 16384;
  float* traj = dh + 32768;
  float* qdg  = dh + 94208;
  float* rdg  = dh + 106496;
  float* out  = (float*)d_out;

  k1_conv1<<<800, 1024, 0, stream>>>(obs, c1w, c1b, p1);
  k2_conv2<<<dim3(200, 4), 256, 0, stream>>>(p1, c2w, c2b, x);
  k3_fc<<<800, 256, 0, stream>>>(x, f1w, f1b, bn1g, bn1b, f2w, f2b, bn2g, bn2b,
                                 eWih, ebih, ebhh, gx);
  k4_enc<<<512, 64, 0, stream>>>(gx, eWhh, dh, dc);
  k5_dec<<<128, 256, 0, stream>>>(obs, dWih, dWhh, dbih, dbhh, ow, ob,
                                  qWih, qWhh, qbih, qbhh, qfw, qfb,
                                  rWih, rWhh, rbih, rbhh, rfw, rfb,
                                  dh, dc, traj, qdg, rdg);
  k6_kf<<<512, 64, 0, stream>>>(obs, traj, qdg, rdg, out);
}

// Round 8
// 700.039 us; speedup vs baseline: 1.0338x; 1.0338x over previous
//
#include <hip/hip_runtime.h>

#define BT 51200      // B*T
#define NB 512        // batch

// ---------- workspace float offsets ----------
#define P1_OFF   ((size_t)0)
#define X_OFF    ((size_t)20480000)
#define GX_OFF   ((size_t)0)

__device__ __forceinline__ float sigf(float x) {
  return __fdividef(1.f, 1.f + __expf(-x));
}
__device__ __forceinline__ float tanhf2(float x) {
  float ax = fabsf(x);
  float e = __expf(-2.f * ax);
  float r = __fdividef(1.f - e, 1.f + e);
  return x < 0.f ? -r : r;
}

// ================= K1: conv1 (SAME 3x3, C=4->16) + relu + 2x2 maxpool =====
// Frozen at best measured config (r5-r7: 164us). Allocator insists on 64
// VGPR (launch_bounds and waves_per_eu both ignored); residual spill is
// ~1-2 slots (WRITE 115 vs 91 ideal) - small. TLP axis exhausted.
__global__ __attribute__((amdgpu_flat_work_group_size(1024, 1024)))
__attribute__((amdgpu_waves_per_eu(4, 4)))
void k1_conv1(const float* __restrict__ obs, const float* __restrict__ w,
              const float* __restrict__ bias, float* __restrict__ p1) {
  __shared__ float xs[64 * 401];
  int tid = threadIdx.x;
  int i0 = blockIdx.x * 64;
  for (int idx = tid; idx < 25600; idx += 1024) {
    int item = idx / 400, feat = idx - item * 400;
    xs[item * 401 + feat] = obs[(size_t)(i0 + item) * 400 + feat];
  }
  __syncthreads();
  int lane = tid & 63;
  int wv = __builtin_amdgcn_readfirstlane(tid >> 6);  // 0..15 = output channel
  const float* xrow = xs + lane * 401;

#define LOADR(R, C, RR) do { \
  int r_ = 2 * p - 1 + (RR); \
  R[0] = 0.f; R[11] = 0.f; \
  if (r_ >= 0 && r_ <= 9) { \
    _Pragma("unroll") \
    for (int j = 0; j < 10; ++j) R[j + 1] = xrow[(C) * 100 + r_ * 10 + j]; \
  } else { \
    _Pragma("unroll") \
    for (int j = 0; j < 10; ++j) R[j + 1] = 0.f; \
  } \
} while (0)

#define FMAU(II, RA, RB, RC, C) do { \
  const float* wa_ = w + wv * 36 + (C) * 9; \
  _Pragma("unroll") \
  for (int q = 0; q < 5; ++q) { \
    _Pragma("unroll") \
    for (int jj = 0; jj < 2; ++jj) { \
      int cb = 2 * q + jj; \
      acc[q][II][jj] += RA[cb] * wa_[0] + RA[cb + 1] * wa_[1] + RA[cb + 2] * wa_[2] \
                      + RB[cb] * wa_[3] + RB[cb + 1] * wa_[4] + RB[cb + 2] * wa_[5] \
                      + RC[cb] * wa_[6] + RC[cb + 1] * wa_[7] + RC[cb + 2] * wa_[8]; \
    } \
  } \
} while (0)

  float b0 = bias[wv];

#pragma unroll 1
  for (int p = 0; p < 5; ++p) {
    float acc[5][2][2];
#pragma unroll
    for (int q = 0; q < 5; ++q)
#pragma unroll
      for (int ii = 0; ii < 2; ++ii)
#pragma unroll
        for (int jj = 0; jj < 2; ++jj) acc[q][ii][jj] = b0;
    float R0[12], R1[12], R2[12], R3[12], R4[12], R5[12];
    LOADR(R0, 0, 0); LOADR(R1, 0, 1); LOADR(R2, 0, 2);
    LOADR(R3, 0, 3); LOADR(R4, 1, 0);
    FMAU(0, R0, R1, R2, 0);
    LOADR(R5, 1, 1); LOADR(R0, 1, 2);
    FMAU(1, R1, R2, R3, 0);
    LOADR(R1, 1, 3); LOADR(R2, 2, 0);
    FMAU(0, R4, R5, R0, 1);
    LOADR(R3, 2, 1); LOADR(R4, 2, 2);
    FMAU(1, R5, R0, R1, 1);
    LOADR(R5, 2, 3); LOADR(R0, 3, 0);
    FMAU(0, R2, R3, R4, 2);
    LOADR(R1, 3, 1); LOADR(R2, 3, 2);
    FMAU(1, R3, R4, R5, 2);
    LOADR(R3, 3, 3);
    FMAU(0, R0, R1, R2, 3);
    FMAU(1, R1, R2, R3, 3);
#pragma unroll
    for (int q = 0; q < 5; ++q) {
      float m = fmaxf(fmaxf(acc[q][0][0], acc[q][0][1]),
                      fmaxf(acc[q][1][0], acc[q][1][1]));
      m = fmaxf(m, 0.f);
      p1[(size_t)(wv * 25 + p * 5 + q) * BT + i0 + lane] = m;
    }
  }
#undef LOADR
#undef FMAU
}

// ================= K2: conv2 (SAME 3x3, 16->32) + relu + 2x2 maxpool ======
// XCD-colocated oc-split: the 4 blocks sharing an item-group g (oc-chunks
// 0..3) re-read the same 16x25 p1 slice. Default dispatch round-robins
// consecutive bids across the 8 XCD L2s, so partners landed on DIFFERENT
// L2s -> 4x fetch from L3/HBM. Bijective remap puts all 4 partners at the
// same bid%8 -> same XCD -> partner re-reads hit that XCD's L2.
// id = (g%8) + 8*(oc + 4*(g>>3)), g in 0..199, oc in 0..3.
__global__ __launch_bounds__(256, 2)
void k2_conv2(const float* __restrict__ p1, const float* __restrict__ w,
              const float* __restrict__ bias, float* __restrict__ x) {
  int bid = blockIdx.x;
  int inner = bid >> 3;
  int oc = inner & 3;
  int g = ((inner >> 2) << 3) | (bid & 7);
  int item = g * 256 + threadIdx.x;
  float acc[8][16];
#pragma unroll
  for (int o = 0; o < 8; ++o) {
    float bv = bias[oc * 8 + o];
#pragma unroll
    for (int pos = 0; pos < 16; ++pos) acc[o][pos] = bv;
  }
#pragma unroll 1
  for (int c = 0; c < 16; ++c) {
    float in[6][6];
#pragma unroll
    for (int t = 0; t < 6; ++t) { in[0][t] = 0.f; in[t][0] = 0.f; }
#pragma unroll
    for (int i = 0; i < 5; ++i)
#pragma unroll
      for (int j = 0; j < 5; ++j)
        in[i + 1][j + 1] = p1[(size_t)(c * 25 + i * 5 + j) * BT + item];
#pragma unroll
    for (int o = 0; o < 8; ++o) {
#pragma unroll
      for (int i = 0; i < 4; ++i)
#pragma unroll
        for (int j = 0; j < 4; ++j) {
          float a = acc[o][i * 4 + j];
#pragma unroll
          for (int dr = 0; dr < 3; ++dr)
#pragma unroll
            for (int dj = 0; dj < 3; ++dj)
              a += in[i + dr][j + dj] * w[((oc * 8 + o) * 16 + c) * 9 + dr * 3 + dj];
          acc[o][i * 4 + j] = a;
        }
    }
  }
#pragma unroll
  for (int o = 0; o < 8; ++o)
#pragma unroll
    for (int p = 0; p < 2; ++p)
#pragma unroll
      for (int q = 0; q < 2; ++q) {
        float m = fmaxf(fmaxf(acc[o][(2 * p) * 4 + 2 * q], acc[o][(2 * p) * 4 + 2 * q + 1]),
                        fmaxf(acc[o][(2 * p + 1) * 4 + 2 * q], acc[o][(2 * p + 1) * 4 + 2 * q + 1]));
        m = fmaxf(m, 0.f);
        x[(size_t)((oc * 8 + o) * 4 + p * 2 + q) * BT + item] = m;
      }
}

// ================= K3: fc1(+bn,relu) -> fc2(+bn,relu) -> eWih projection ===
__global__ __launch_bounds__(256, 2)
void k3_fc(const float* __restrict__ x,
           const float* __restrict__ f1w, const float* __restrict__ f1b,
           const float* __restrict__ bn1g, const float* __restrict__ bn1b,
           const float* __restrict__ f2w, const float* __restrict__ f2b,
           const float* __restrict__ bn2g, const float* __restrict__ bn2b,
           const float* __restrict__ eWih, const float* __restrict__ ebih,
           const float* __restrict__ ebhh, float* __restrict__ gx) {
  __shared__ float xs[128 * 64];
  __shared__ float ys[128 * 64];
  const float BNRS = 0.9999950000374997f;  // 1/sqrt(1+1e-5)
  int tid = threadIdx.x;
  int lane = tid & 63;
  int wv = __builtin_amdgcn_readfirstlane(tid >> 6);
  int i0 = blockIdx.x * 64;
#pragma unroll
  for (int r = 0; r < 32; ++r) {
    int k = r * 4 + (tid >> 6);
    xs[k * 64 + lane] = x[(size_t)k * BT + i0 + lane];
  }
  __syncthreads();
#pragma unroll 1
  for (int jj = 0; jj < 8; ++jj) {
    int j0 = wv * 32 + jj * 4;
    float a[4] = {0.f, 0.f, 0.f, 0.f};
#pragma unroll 8
    for (int k = 0; k < 128; ++k) {
      float xv = xs[k * 64 + lane];
#pragma unroll
      for (int u = 0; u < 4; ++u) a[u] += xv * f1w[(j0 + u) * 128 + k];
    }
#pragma unroll
    for (int u = 0; u < 4; ++u) {
      int j = j0 + u;
      float v = a[u] + f1b[j];
      v = bn1g[j] * v * BNRS + bn1b[j];
      ys[j * 64 + lane] = fmaxf(v, 0.f);
    }
  }
  __syncthreads();
#pragma unroll 1
  for (int jj = 0; jj < 4; ++jj) {
    int j0 = wv * 16 + jj * 4;
    float a[4] = {0.f, 0.f, 0.f, 0.f};
#pragma unroll 8
    for (int k = 0; k < 128; ++k) {
      float yv = ys[k * 64 + lane];
#pragma unroll
      for (int u = 0; u < 4; ++u) a[u] += yv * f2w[(j0 + u) * 128 + k];
    }
#pragma unroll
    for (int u = 0; u < 4; ++u) {
      int j = j0 + u;
      float v = a[u] + f2b[j];
      v = bn2g[j] * v * BNRS + bn2b[j];
      xs[j * 64 + lane] = fmaxf(v, 0.f);
    }
  }
  __syncthreads();
#pragma unroll 1
  for (int jj = 0; jj < 8; ++jj) {
    int j0 = wv * 32 + jj * 4;
    float a[4] = {0.f, 0.f, 0.f, 0.f};
#pragma unroll 8
    for (int k = 0; k < 64; ++k) {
      float zv = xs[k * 64 + lane];
#pragma unroll
      for (int u = 0; u < 4; ++u) a[u] += zv * eWih[(j0 + u) * 64 + k];
    }
#pragma unroll
    for (int u = 0; u < 4; ++u) {
      int j = j0 + u;
      gx[(size_t)j * BT + i0 + lane] = a[u] + ebih[j] + ebhh[j];
    }
  }
}

// ====== K456: fused encoder LSTM + decoder/physics/QR + Kalman filter =====
// One 64-lane wave carries batch b through all phases; h/c/qdiag/rdiag in
// registers, traj in LDS. Weight tables staged into a reused 32KB arena
// with phase barriers (waves are in lockstep: same T=100 / 5-step shapes).
// Arithmetic order identical to the previous k4/k5/k6 -> bitwise-same out.
// 256 blocks x 2 waves = 512 waves = 2/CU on all CUs (same TLP as before,
// minus 2 launches, minus dh/dc/traj/qdg/rdg global round-trips).
__global__ __launch_bounds__(128, 2)
void k456(const float* __restrict__ obs, const float* __restrict__ gx,
          const float* __restrict__ eWhh,
          const float* __restrict__ dWih, const float* __restrict__ dWhh,
          const float* __restrict__ dbih, const float* __restrict__ dbhh,
          const float* __restrict__ ow, const float* __restrict__ ob,
          const float* __restrict__ qWih, const float* __restrict__ qWhh,
          const float* __restrict__ qbih, const float* __restrict__ qbhh,
          const float* __restrict__ qfw, const float* __restrict__ qfb,
          const float* __restrict__ rWih, const float* __restrict__ rWhh,
          const float* __restrict__ rbih, const float* __restrict__ rbhh,
          const float* __restrict__ rfw, const float* __restrict__ rfb,
          float* __restrict__ out) {
  __shared__ float arena[8064];   // phased: wT(4096) | dwT+owT+dbs(4608) | ihT+hhT+fwT+bs(8064)
  __shared__ float tL2[2 * 120];
  int tid = threadIdx.x;
  int lane = tid & 63, w = tid >> 6;   // w in 0..1
  int b = blockIdx.x * 2 + w;
  float* tL = tL2 + w * 120;
  int xl = (lane & 31) + 32;
  int l12 = lane < 12 ? lane : 0;
  int l24 = lane < 24 ? lane : 0;

  // ---------- Phase A: encoder LSTM (T=100) ----------
  for (int idx = tid; idx < 4096; idx += 128) {
    int g = idx & 127, k = idx >> 7;
    arena[k * 128 + g] = eWhh[g * 32 + k];
  }
  __syncthreads();
  float cc = 0.f, hh = 0.f;
  size_t base0 = (size_t)b * 100;
  float ga_n = gx[(size_t)lane * BT + base0];
  float gb_n = gx[(size_t)(lane + 64) * BT + base0];
#pragma unroll 1
  for (int t = 0; t < 100; ++t) {
    float ga = ga_n, gb2 = gb_n;
    if (t < 99) {
      ga_n = gx[(size_t)lane * BT + base0 + t + 1];
      gb_n = gx[(size_t)(lane + 64) * BT + base0 + t + 1];
    }
#pragma unroll
    for (int k = 0; k < 32; ++k) {
      float hk = __shfl(hh, k);
      ga += hk * arena[k * 128 + lane];
      gb2 += hk * arena[k * 128 + lane + 64];
    }
    float gaX = __shfl(ga, xl);
    float gbX = __shfl(gb2, xl);
    if (lane < 32) {
      float ig = sigf(ga), fg = sigf(gaX);
      float gg = tanhf2(gb2), og = sigf(gbX);
      cc = fg * cc + ig * gg;
      hh = og * tanhf2(cc);
    }
  }

  // ---------- Phase B: decoder LSTM (5 steps) + physics ----------
  __syncthreads();
  for (int idx = tid; idx < 4096; idx += 128) {
    int k = idx >> 7, g = idx & 127;
    arena[idx] = dWih[g * 32 + k] + dWhh[g * 32 + k];  // din==dh every step
  }
  for (int idx = tid; idx < 384; idx += 128) {
    int k = idx / 12, j = idx - k * 12;
    arena[4096 + idx] = ow[j * 32 + k];
  }
  for (int idx = tid; idx < 128; idx += 128)
    arena[4480 + idx] = dbih[idx] + dbhh[idx];
  __syncthreads();
  {
    const float* dwT = arena;
    const float* owT = arena + 4096;
    const float* dbs = arena + 4480;
    float aReg[5];
#pragma unroll 1
    for (int s = 0; s < 5; ++s) {
      float ga = dbs[lane], gb2 = dbs[lane + 64];
#pragma unroll
      for (int k = 0; k < 32; ++k) {
        float hk = __shfl(hh, k);
        ga += hk * dwT[k * 128 + lane];
        gb2 += hk * dwT[k * 128 + lane + 64];
      }
      float gaX = __shfl(ga, xl);
      float gbX = __shfl(gb2, xl);
      if (lane < 32) {
        float ig = sigf(ga), fg = sigf(gaX);
        float gg = tanhf2(gb2), og = sigf(gbX);
        cc = fg * cc + ig * gg;
        hh = og * tanhf2(cc);
      }
      float pa = ob[l12];
#pragma unroll
      for (int k = 0; k < 32; ++k) pa += __shfl(hh, k) * owT[k * 12 + l12];
      aReg[s] = pa;
    }
    // physics integration -> tL
    if (lane < 12) {
      int n = lane >> 1, d = lane & 1;
      float v0 = 0.f, p0 = 0.f;
      if (n == 0) {
        p0 = obs[(size_t)b * 40000 + 39600 + d];
        v0 = obs[(size_t)b * 40000 + 39600 + 2 + d];
      }
      float vc = v0, pc = p0;
#pragma unroll
      for (int s = 0; s < 5; ++s) {
        float a = aReg[s];
        vc += 0.1f * a;
        pc += vc * 0.1f + a * 0.005f;
        tL[s * 24 + n * 4 + d] = pc;
        tL[s * 24 + n * 4 + 2 + d] = vc;
      }
    }
  }

  // ---------- Phase C: Q then R LSTMs over traj ----------
  float qdiag = 0.f, rdiag = 0.f;
#pragma unroll 1
  for (int qr = 0; qr < 2; ++qr) {
    __syncthreads();
    const float* Wih = qr ? rWih : qWih;
    const float* Whh = qr ? rWhh : qWhh;
    const float* bih = qr ? rbih : qbih;
    const float* bhh = qr ? rbhh : qbhh;
    const float* fw  = qr ? rfw  : qfw;
    const float* fb  = qr ? rfb  : qfb;
    for (int idx = tid; idx < 3072; idx += 128) {
      int k = idx >> 7, g = idx & 127;
      arena[idx] = Wih[g * 24 + k];
    }
    for (int idx = tid; idx < 4096; idx += 128) {
      int k = idx >> 7, g = idx & 127;
      arena[3072 + idx] = Whh[g * 32 + k];
    }
    for (int idx = tid; idx < 768; idx += 128) {
      int k = idx / 24, j = idx - k * 24;
      arena[7168 + idx] = fw[j * 32 + k];
    }
    for (int idx = tid; idx < 128; idx += 128)
      arena[7936 + idx] = bih[idx] + bhh[idx];
    __syncthreads();
    const float* ihT = arena;
    const float* hhT = arena + 3072;
    const float* fwT = arena + 7168;
    const float* bs  = arena + 7936;
    hh = 0.f;
    cc = 0.f;
#pragma unroll 1
    for (int s = 0; s < 5; ++s) {
      float ga = bs[lane], gb2 = bs[lane + 64];
#pragma unroll
      for (int k = 0; k < 24; ++k) {
        float z = tL[s * 24 + k];
        ga += z * ihT[k * 128 + lane];
        gb2 += z * ihT[k * 128 + lane + 64];
      }
#pragma unroll
      for (int k = 0; k < 32; ++k) {
        float hk = __shfl(hh, k);
        ga += hk * hhT[k * 128 + lane];
        gb2 += hk * hhT[k * 128 + lane + 64];
      }
      float gaX = __shfl(ga, xl);
      float gbX = __shfl(gb2, xl);
      if (lane < 32) {
        float ig = sigf(ga), fg = sigf(gaX);
        float gg = tanhf2(gb2), og = sigf(gbX);
        cc = fg * cc + ig * gg;
        hh = og * tanhf2(cc);
      }
    }
    float qv = fb[l24];
#pragma unroll
    for (int k = 0; k < 32; ++k) qv += __shfl(hh, k) * fwT[k * 24 + l24];
    if (qr == 0) qdiag = fabsf(qv); else rdiag = fabsf(qv);
  }

  // ---------- Phase D: Kalman filter (register-resident, shfl-only) ------
  {
    float sv = 0.f, qv = 0.f, rv = 0.f;
    if (lane < 24) {
      sv = (lane < 4) ? obs[(size_t)b * 40000 + 39600 + lane] : 0.f;
      qv = qdiag;
      rv = rdiag;
    }
    float p[24];
#pragma unroll
    for (int i = 0; i < 24; ++i) p[i] = (i == lane) ? 1.f : 0.f;
    const int srcPF = ((lane & 3) < 2) ? (lane + 2) : lane;
    const int srcA = (lane < 24) ? lane : (lane - 24);
#pragma unroll 1
    for (int s = 0; s < 5; ++s) {
      float sshift = __shfl(sv, srcPF);
      float smv = sv + (((lane & 3) < 2) ? 0.1f * sshift : 0.f);
#pragma unroll
      for (int i = 0; i < 24; ++i)
        if ((i & 3) < 2) p[i] += 0.1f * p[i + 2];
#pragma unroll
      for (int i = 0; i < 24; ++i) {
        float t = __shfl(p[i], srcPF);
        if ((lane & 3) < 2) p[i] += 0.1f * t;
      }
#pragma unroll
      for (int i = 0; i < 24; ++i) p[i] += (i == lane) ? qv : 0.f;
      float a[24];
#pragma unroll
      for (int i = 0; i < 24; ++i) {
        float t = __shfl(p[i], srcA);
        a[i] = (lane < 24) ? (p[i] + ((i == lane) ? rv : 0.f)) : t;
      }
#pragma unroll
      for (int k = 0; k < 24; ++k) {
        float piv = __shfl(a[k], k);
        float inv = 1.f / piv;
        float t = a[k] * inv;
#pragma unroll
        for (int i = 0; i < 24; ++i) {
          if (i != k) {
            float fi = __shfl(a[i], k);
            a[i] = fmaf(-fi, t, a[i]);
          }
        }
        a[k] = t;
      }
      float zv = tL[s * 24 + l24];
      float innv = zv - smv;
      float acc = 0.f;
#pragma unroll
      for (int m = 0; m < 24; ++m) acc += a[m] * __shfl(innv, m);
      float kupd = __shfl(acc, 24 + l24);
      sv = smv + kupd;
      if (lane < 24) out[(size_t)b * 120 + s * 24 + lane] = sv;
      float pn[24];
#pragma unroll
      for (int i = 0; i < 24; ++i) {
        float acc2 = 0.f;
#pragma unroll
        for (int k = 0; k < 24; ++k) acc2 += __shfl(a[k], 24 + i) * p[k];
        pn[i] = p[i] - acc2;
      }
#pragma unroll
      for (int i = 0; i < 24; ++i) p[i] = pn[i];
    }
  }
}

// =========================================================================
extern "C" void kernel_launch(void* const* d_in, const int* in_sizes, int n_in,
                              void* d_out, int out_size, void* d_ws, size_t ws_size,
                              hipStream_t stream) {
  (void)in_sizes; (void)n_in; (void)out_size; (void)ws_size;
  const float* obs  = (const float*)d_in[0];
  const float* c1w  = (const float*)d_in[1];
  const float* c1b  = (const float*)d_in[2];
  const float* c2w  = (const float*)d_in[3];
  const float* c2b  = (const float*)d_in[4];
  const float* f1w  = (const float*)d_in[5];
  const float* f1b  = (const float*)d_in[6];
  const float* bn1g = (const float*)d_in[7];
  const float* bn1b = (const float*)d_in[8];
  const float* f2w  = (const float*)d_in[9];
  const float* f2b  = (const float*)d_in[10];
  const float* bn2g = (const float*)d_in[11];
  const float* bn2b = (const float*)d_in[12];
  const float* eWih = (const float*)d_in[13];
  const float* eWhh = (const float*)d_in[14];
  const float* ebih = (const float*)d_in[15];
  const float* ebhh = (const float*)d_in[16];
  const float* dWih = (const float*)d_in[17];
  const float* dWhh = (const float*)d_in[18];
  const float* dbih = (const float*)d_in[19];
  const float* dbhh = (const float*)d_in[20];
  const float* ow   = (const float*)d_in[21];
  const float* ob   = (const float*)d_in[22];
  const float* qWih = (const float*)d_in[23];
  const float* qWhh = (const float*)d_in[24];
  const float* qbih = (const float*)d_in[25];
  const float* qbhh = (const float*)d_in[26];
  const float* qfw  = (const float*)d_in[27];
  const float* qfb  = (const float*)d_in[28];
  const float* rWih = (const float*)d_in[29];
  const float* rWhh = (const float*)d_in[30];
  const float* rbih = (const float*)d_in[31];
  const float* rbhh = (const float*)d_in[32];
  const float* rfw  = (const float*)d_in[33];
  const float* rfb  = (const float*)d_in[34];

  float* ws = (float*)d_ws;
  float* p1   = ws + P1_OFF;
  float* x    = ws + X_OFF;
  float* gx   = ws + GX_OFF;       // reuses p1 region (dead after k2)
  float* out  = (float*)d_out;

  k1_conv1<<<800, 1024, 0, stream>>>(obs, c1w, c1b, p1);
  k2_conv2<<<800, 256, 0, stream>>>(p1, c2w, c2b, x);
  k3_fc<<<800, 256, 0, stream>>>(x, f1w, f1b, bn1g, bn1b, f2w, f2b, bn2g, bn2b,
                                 eWih, ebih, ebhh, gx);
  k456<<<256, 128, 0, stream>>>(obs, gx, eWhh,
                                dWih, dWhh, dbih, dbhh, ow, ob,
                                qWih, qWhh, qbih, qbhh, qfw, qfb,
                                rWih, rWhh, rbih, rbhh, rfw, rfb,
                                out);
}